// Round 1
// baseline (262.053 us; speedup 1.0000x reference)
//
#include <hip/hip_runtime.h>
#include <math.h>

#define N_ROWS 4096
#define D_DIM  256
#define TILE   64
#define INV_T  (1.0f / 0.07f)

// ---------------------------------------------------------------------------
// K0: zero the per-row accumulators (ws is poisoned 0xAA before every call)
// ---------------------------------------------------------------------------
__global__ void zero_k(float* __restrict__ p, int n) {
    int i = blockIdx.x * 256 + threadIdx.x;
    if (i < n) p[i] = 0.0f;
}

// ---------------------------------------------------------------------------
// K1: row-normalize features. One 256-thread block per row (D == 256).
// ---------------------------------------------------------------------------
__global__ __launch_bounds__(256) void normalize_k(const float* __restrict__ f,
                                                   float* __restrict__ fn) {
    const int row = blockIdx.x;
    const int t = threadIdx.x;
    float v = f[(size_t)row * D_DIM + t];
    float s = v * v;
    #pragma unroll
    for (int off = 32; off > 0; off >>= 1) s += __shfl_xor(s, off, 64);
    __shared__ float wsum[4];
    if ((t & 63) == 0) wsum[t >> 6] = s;
    __syncthreads();
    float tot = wsum[0] + wsum[1] + wsum[2] + wsum[3];
    float norm = fmaxf(sqrtf(tot), 1e-8f);
    fn[(size_t)row * D_DIM + t] = v / norm;
}

// ---------------------------------------------------------------------------
// K2: fused 64x64-tile fp32 GEMM (cosim) + mask epilogue.
// Accumulates per-row: accum[i] = neg, accum[N+i] = sum(cosim*pm),
// accum[2N+i] = npos. Never materializes the NxN matrix.
// Block = 256 threads as 16x16 thread grid, 4x4 outputs each.
// LDS tiles stored K-major ([k][row]) so the inner loop reads float4.
// ---------------------------------------------------------------------------
__global__ __launch_bounds__(256) void fused_k(const float* __restrict__ fn,
                                               const float* __restrict__ pm,
                                               const float* __restrict__ nm,
                                               float* __restrict__ accum) {
    __shared__ float As[TILE * TILE];  // [k][row]
    __shared__ float Bs[TILE * TILE];  // [k][col]

    const int i0 = blockIdx.y * TILE;
    const int j0 = blockIdx.x * TILE;
    const int t  = threadIdx.x;
    const int tx = t & 15;        // col group
    const int ty = t >> 4;        // row group

    // load mapping: 4 threads per row, 16 consecutive k each (4 x float4)
    const int lrow = t >> 2;            // 0..63
    const int lseg = (t & 3) * 16;      // 0,16,32,48

    float acc[4][4] = {{0.f}};

    for (int k0 = 0; k0 < D_DIM; k0 += TILE) {
        const float4* ap = (const float4*)(fn + (size_t)(i0 + lrow) * D_DIM + k0 + lseg);
        const float4* bp = (const float4*)(fn + (size_t)(j0 + lrow) * D_DIM + k0 + lseg);
        #pragma unroll
        for (int q = 0; q < 4; ++q) {
            float4 av = ap[q];
            float4 bv = bp[q];
            const int kb = lseg + q * 4;
            As[(kb + 0) * TILE + lrow] = av.x;
            As[(kb + 1) * TILE + lrow] = av.y;
            As[(kb + 2) * TILE + lrow] = av.z;
            As[(kb + 3) * TILE + lrow] = av.w;
            Bs[(kb + 0) * TILE + lrow] = bv.x;
            Bs[(kb + 1) * TILE + lrow] = bv.y;
            Bs[(kb + 2) * TILE + lrow] = bv.z;
            Bs[(kb + 3) * TILE + lrow] = bv.w;
        }
        __syncthreads();

        #pragma unroll 8
        for (int kk = 0; kk < TILE; ++kk) {
            float4 a4 = *(const float4*)&As[kk * TILE + ty * 4];
            float4 b4 = *(const float4*)&Bs[kk * TILE + tx * 4];
            acc[0][0] = fmaf(a4.x, b4.x, acc[0][0]);
            acc[0][1] = fmaf(a4.x, b4.y, acc[0][1]);
            acc[0][2] = fmaf(a4.x, b4.z, acc[0][2]);
            acc[0][3] = fmaf(a4.x, b4.w, acc[0][3]);
            acc[1][0] = fmaf(a4.y, b4.x, acc[1][0]);
            acc[1][1] = fmaf(a4.y, b4.y, acc[1][1]);
            acc[1][2] = fmaf(a4.y, b4.z, acc[1][2]);
            acc[1][3] = fmaf(a4.y, b4.w, acc[1][3]);
            acc[2][0] = fmaf(a4.z, b4.x, acc[2][0]);
            acc[2][1] = fmaf(a4.z, b4.y, acc[2][1]);
            acc[2][2] = fmaf(a4.z, b4.z, acc[2][2]);
            acc[2][3] = fmaf(a4.z, b4.w, acc[2][3]);
            acc[3][0] = fmaf(a4.w, b4.x, acc[3][0]);
            acc[3][1] = fmaf(a4.w, b4.y, acc[3][1]);
            acc[3][2] = fmaf(a4.w, b4.z, acc[3][2]);
            acc[3][3] = fmaf(a4.w, b4.w, acc[3][3]);
        }
        __syncthreads();
    }

    // Epilogue: masks + exp + per-row partial sums
    #pragma unroll
    for (int r = 0; r < 4; ++r) {
        const int i  = i0 + ty * 4 + r;
        const int jb = j0 + tx * 4;
        float4 pmv = *(const float4*)(pm + (size_t)i * N_ROWS + jb);
        float4 nmv = *(const float4*)(nm + (size_t)i * N_ROWS + jb);
        float pmm[4] = {pmv.x, pmv.y, pmv.z, pmv.w};
        float nmm[4] = {nmv.x, nmv.y, nmv.z, nmv.w};
        float negp = 0.f, posp = 0.f, np = 0.f;
        #pragma unroll
        for (int c = 0; c < 4; ++c) {
            const int j = jb + c;
            float cs   = acc[r][c] * INV_T;
            float keep = (j == i) ? 0.f : 1.f;
            float p    = pmm[c] * keep;
            float nmk  = nmm[c] * keep;
            negp = fmaf(__expf(cs), nmk, negp);
            posp = fmaf(cs, p, posp);
            np  += p;
        }
        // reduce across the 16 tx lanes (same ty) within the wave
        #pragma unroll
        for (int off = 1; off < 16; off <<= 1) {
            negp += __shfl_xor(negp, off, 64);
            posp += __shfl_xor(posp, off, 64);
            np   += __shfl_xor(np,   off, 64);
        }
        if (tx == 0) {
            atomicAdd(&accum[i], negp);
            atomicAdd(&accum[N_ROWS + i], posp);
            atomicAdd(&accum[2 * N_ROWS + i], np);
        }
    }
}

// ---------------------------------------------------------------------------
// K3: final reduction over rows -> scalar loss
// ---------------------------------------------------------------------------
__global__ __launch_bounds__(256) void final_k(const float* __restrict__ accum,
                                               float* __restrict__ out) {
    const int t = threadIdx.x;
    float s = 0.f;
    for (int i = t; i < N_ROWS; i += 256) {
        float neg  = accum[i];
        float posc = accum[N_ROWS + i];
        float np   = accum[2 * N_ROWS + i];
        float term = (np > 0.f) ? (posc - np * logf(fmaxf(neg, 1e-30f))) / np : 0.f;
        s += term;
    }
    #pragma unroll
    for (int off = 32; off > 0; off >>= 1) s += __shfl_xor(s, off, 64);
    __shared__ float wsum[4];
    if ((t & 63) == 0) wsum[t >> 6] = s;
    __syncthreads();
    if (t == 0) {
        float tot = wsum[0] + wsum[1] + wsum[2] + wsum[3];
        out[0] = -tot / (float)N_ROWS;
    }
}

// ---------------------------------------------------------------------------
extern "C" void kernel_launch(void* const* d_in, const int* in_sizes, int n_in,
                              void* d_out, int out_size, void* d_ws, size_t ws_size,
                              hipStream_t stream) {
    const float* feat = (const float*)d_in[0];
    const float* pm   = (const float*)d_in[1];
    const float* nm   = (const float*)d_in[2];
    float* out  = (float*)d_out;

    float* fn    = (float*)d_ws;                  // N*D floats (4 MB)
    float* accum = fn + (size_t)N_ROWS * D_DIM;   // 3*N floats

    zero_k<<<(3 * N_ROWS + 255) / 256, 256, 0, stream>>>(accum, 3 * N_ROWS);
    normalize_k<<<N_ROWS, 256, 0, stream>>>(feat, fn);

    dim3 grid(N_ROWS / TILE, N_ROWS / TILE);
    fused_k<<<grid, 256, 0, stream>>>(fn, pm, nm, accum);

    final_k<<<1, 256, 0, stream>>>(accum, out);
}

// Round 2
// 187.715 us; speedup vs baseline: 1.3960x; 1.3960x over previous
//
#include <hip/hip_runtime.h>
#include <math.h>

#define N_ROWS 4096
#define D_DIM  256
#define INV_T  (1.0f / 0.07f)

typedef _Float16 half8 __attribute__((ext_vector_type(8)));
typedef _Float16 half4 __attribute__((ext_vector_type(4)));
typedef float    f32x4 __attribute__((ext_vector_type(4)));

#define GLOAD_LDS(gp, lp) \
    __builtin_amdgcn_global_load_lds( \
        (const __attribute__((address_space(1))) void*)(gp), \
        (__attribute__((address_space(3))) void*)(lp), 16, 0, 0)

// ---------------------------------------------------------------------------
// K0: zero the per-row accumulators
// ---------------------------------------------------------------------------
__global__ void zero_k(float* __restrict__ p, int n) {
    int i = blockIdx.x * 256 + threadIdx.x;
    if (i < n) p[i] = 0.0f;
}

// ---------------------------------------------------------------------------
// K1: row-normalize features -> fp16. One wave per row (4 rows/block).
// ---------------------------------------------------------------------------
__global__ __launch_bounds__(256) void normalize_k(const float* __restrict__ f,
                                                   _Float16* __restrict__ fnh) {
    const int t    = threadIdx.x;
    const int lane = t & 63;
    const int row  = blockIdx.x * 4 + (t >> 6);
    float4 v = ((const float4*)(f + (size_t)row * D_DIM))[lane];
    float s = v.x * v.x + v.y * v.y + v.z * v.z + v.w * v.w;
    #pragma unroll
    for (int off = 32; off > 0; off >>= 1) s += __shfl_xor(s, off, 64);
    float rn = 1.0f / fmaxf(sqrtf(s), 1e-8f);
    half4 h;
    h.x = (_Float16)(v.x * rn);
    h.y = (_Float16)(v.y * rn);
    h.z = (_Float16)(v.z * rn);
    h.w = (_Float16)(v.w * rn);
    *(half4*)(fnh + (size_t)row * D_DIM + lane * 4) = h;
}

// ---------------------------------------------------------------------------
// K2: fused MFMA cosim + mask epilogue.
// Block = 256 threads (4 waves), tile 128x128, BK=64, K=256 (4 iters).
// Wave w: (w>>1, w&1) -> 64x64 subtile = 4x4 MFMA 16x16x32_f16 tiles.
// LDS: As/Bs [128][64] half, unpadded (global_load_lds lane-contiguous).
// ---------------------------------------------------------------------------
__global__ __launch_bounds__(256) void fused_k(const _Float16* __restrict__ fnh,
                                               const float* __restrict__ pm,
                                               const float* __restrict__ nm,
                                               float* __restrict__ accum) {
    __shared__ __align__(16) _Float16 As[128 * 64];
    __shared__ __align__(16) _Float16 Bs[128 * 64];

    const int t    = threadIdx.x;
    const int lane = t & 63;
    const int w    = t >> 6;        // wave 0..3
    const int wr   = w >> 1;        // wave row half (0..1)
    const int wc   = w & 1;         // wave col half (0..1)
    const int i0   = blockIdx.y * 128;
    const int j0   = blockIdx.x * 128;

    const int l15  = lane & 15;
    const int grp  = lane >> 4;     // 0..3

    // staging address components (issue q covers 32 rows; 8 threads/row)
    const int srow = t >> 3;        // 0..31
    const int scol = (t & 7) * 8;   // 0,8,...,56 halfs

    f32x4 acc[4][4];
    #pragma unroll
    for (int a = 0; a < 4; ++a)
        #pragma unroll
        for (int b = 0; b < 4; ++b)
            acc[a][b] = (f32x4){0.f, 0.f, 0.f, 0.f};

    for (int k0 = 0; k0 < D_DIM; k0 += 64) {
        #pragma unroll
        for (int q = 0; q < 4; ++q) {
            GLOAD_LDS(fnh + (size_t)(i0 + q * 32 + srow) * D_DIM + k0 + scol,
                      &As[q * 2048 + w * 512]);
            GLOAD_LDS(fnh + (size_t)(j0 + q * 32 + srow) * D_DIM + k0 + scol,
                      &Bs[q * 2048 + w * 512]);
        }
        __syncthreads();

        #pragma unroll
        for (int kk = 0; kk < 2; ++kk) {
            half8 af[4], bf[4];
            #pragma unroll
            for (int mt = 0; mt < 4; ++mt)
                af[mt] = *(const half8*)&As[(wr * 64 + mt * 16 + l15) * 64 + kk * 32 + grp * 8];
            #pragma unroll
            for (int nt = 0; nt < 4; ++nt)
                bf[nt] = *(const half8*)&Bs[(wc * 64 + nt * 16 + l15) * 64 + kk * 32 + grp * 8];
            #pragma unroll
            for (int mt = 0; mt < 4; ++mt)
                #pragma unroll
                for (int nt = 0; nt < 4; ++nt)
                    acc[mt][nt] = __builtin_amdgcn_mfma_f32_16x16x32_f16(
                        af[mt], bf[nt], acc[mt][nt], 0, 0, 0);
        }
        __syncthreads();
    }

    // Epilogue. C/D layout: col = lane&15, row = grp*4 + reg.
    #pragma unroll
    for (int mt = 0; mt < 4; ++mt) {
        #pragma unroll
        for (int reg = 0; reg < 4; ++reg) {
            const int i = i0 + wr * 64 + mt * 16 + grp * 4 + reg;
            float negp = 0.f, posp = 0.f, np = 0.f;
            #pragma unroll
            for (int nt = 0; nt < 4; ++nt) {
                const int j  = j0 + wc * 64 + nt * 16 + l15;
                float cs     = acc[mt][nt][reg] * INV_T;
                float p      = pm[(size_t)i * N_ROWS + j];
                float nmv    = nm[(size_t)i * N_ROWS + j];
                float keep   = (i == j) ? 0.f : 1.f;
                p   *= keep;
                nmv *= keep;
                negp = fmaf(__expf(cs), nmv, negp);
                posp = fmaf(cs, p, posp);
                np  += p;
            }
            #pragma unroll
            for (int off = 1; off < 16; off <<= 1) {
                negp += __shfl_xor(negp, off, 64);
                posp += __shfl_xor(posp, off, 64);
                np   += __shfl_xor(np,   off, 64);
            }
            if (l15 == 0) {
                atomicAdd(&accum[i], negp);
                atomicAdd(&accum[N_ROWS + i], posp);
                atomicAdd(&accum[2 * N_ROWS + i], np);
            }
        }
    }
}

// ---------------------------------------------------------------------------
// K3: final reduction over rows -> scalar loss
// ---------------------------------------------------------------------------
__global__ __launch_bounds__(256) void final_k(const float* __restrict__ accum,
                                               float* __restrict__ out) {
    const int t = threadIdx.x;
    float s = 0.f;
    for (int i = t; i < N_ROWS; i += 256) {
        float neg  = accum[i];
        float posc = accum[N_ROWS + i];
        float np   = accum[2 * N_ROWS + i];
        float term = (np > 0.f) ? (posc - np * logf(fmaxf(neg, 1e-30f))) / np : 0.f;
        s += term;
    }
    #pragma unroll
    for (int off = 32; off > 0; off >>= 1) s += __shfl_xor(s, off, 64);
    __shared__ float wsum[4];
    if ((t & 63) == 0) wsum[t >> 6] = s;
    __syncthreads();
    if (t == 0) {
        float tot = wsum[0] + wsum[1] + wsum[2] + wsum[3];
        out[0] = -tot / (float)N_ROWS;
    }
}

// ---------------------------------------------------------------------------
extern "C" void kernel_launch(void* const* d_in, const int* in_sizes, int n_in,
                              void* d_out, int out_size, void* d_ws, size_t ws_size,
                              hipStream_t stream) {
    const float* feat = (const float*)d_in[0];
    const float* pm   = (const float*)d_in[1];
    const float* nm   = (const float*)d_in[2];
    float* out = (float*)d_out;

    _Float16* fnh  = (_Float16*)d_ws;                      // N*D halfs (2 MB)
    float* accum   = (float*)(fnh + (size_t)N_ROWS * D_DIM); // 3*N floats

    zero_k<<<(3 * N_ROWS + 255) / 256, 256, 0, stream>>>(accum, 3 * N_ROWS);
    normalize_k<<<N_ROWS / 4, 256, 0, stream>>>(feat, fnh);

    dim3 grid(N_ROWS / 128, N_ROWS / 128);
    fused_k<<<grid, 256, 0, stream>>>(fnh, pm, nm, accum);

    final_k<<<1, 256, 0, stream>>>(accum, out);
}

// Round 3
// 179.029 us; speedup vs baseline: 1.4637x; 1.0485x over previous
//
#include <hip/hip_runtime.h>
#include <math.h>

#define N_ROWS 4096
#define D_DIM  256
#define INV_T  (1.0f / 0.07f)

typedef _Float16 half8 __attribute__((ext_vector_type(8)));
typedef _Float16 half4 __attribute__((ext_vector_type(4)));
typedef float    f32x4 __attribute__((ext_vector_type(4)));

#define GLOAD_LDS(gp, lp) \
    __builtin_amdgcn_global_load_lds( \
        (const __attribute__((address_space(1))) void*)(gp), \
        (__attribute__((address_space(3))) void*)(lp), 16, 0, 0)

// ---------------------------------------------------------------------------
// K1: row-normalize features -> fp16 (one wave per row) + zero accum.
// ---------------------------------------------------------------------------
__global__ __launch_bounds__(256) void normalize_k(const float* __restrict__ f,
                                                   _Float16* __restrict__ fnh,
                                                   float* __restrict__ accum) {
    const int t   = threadIdx.x;
    const int gid = blockIdx.x * 256 + t;
    if (gid < 3 * N_ROWS) accum[gid] = 0.0f;

    const int lane = t & 63;
    const int row  = blockIdx.x * 4 + (t >> 6);
    float4 v = ((const float4*)(f + (size_t)row * D_DIM))[lane];
    float s = v.x * v.x + v.y * v.y + v.z * v.z + v.w * v.w;
    #pragma unroll
    for (int off = 32; off > 0; off >>= 1) s += __shfl_xor(s, off, 64);
    float rn = 1.0f / fmaxf(sqrtf(s), 1e-8f);
    half4 h;
    h.x = (_Float16)(v.x * rn);
    h.y = (_Float16)(v.y * rn);
    h.z = (_Float16)(v.z * rn);
    h.w = (_Float16)(v.w * rn);
    *(half4*)(fnh + (size_t)row * D_DIM + lane * 4) = h;
}

// ---------------------------------------------------------------------------
// K2: fused MFMA cosim + mask epilogue.
// Tile 128x128, BK=64, 4 waves (wr,wc) each 64x64 = 4x4 MFMA 16x16x32_f16.
// OPERANDS SWAPPED vs naive: A = j-rows (Bs), B = i-rows (As), so in C/D:
//   i = l15 side, j = grp*4+reg side  -> float4 mask loads, 2-step reduce.
// LDS XOR swizzle: granule (row r, slot s) holds source col-seg s^(r&7);
// keeps global_load_lds lane-contiguity AND makes ds_read_b128 conflict-free
// (round-2 layout was a 16-way conflict: row stride = exactly 32 banks).
// ---------------------------------------------------------------------------
__global__ __launch_bounds__(256, 4) void fused_k(const _Float16* __restrict__ fnh,
                                                  const float* __restrict__ pm,
                                                  const float* __restrict__ nm,
                                                  float* __restrict__ accum) {
    __shared__ __align__(16) _Float16 As[128 * 64];
    __shared__ __align__(16) _Float16 Bs[128 * 64];

    const int t    = threadIdx.x;
    const int lane = t & 63;
    const int w    = t >> 6;
    const int wr   = w >> 1;
    const int wc   = w & 1;
    const int i0   = blockIdx.y * 128;
    const int j0   = blockIdx.x * 128;
    const int l15  = lane & 15;
    const int grp  = lane >> 4;

    // staging: 8 lanes/row, XOR-swizzled column segment (halfs)
    const int srow = t >> 3;                              // 0..31 per q
    const int sseg = ((t & 7) ^ ((t >> 3) & 7)) * 8;      // swizzled 16B granule

    f32x4 acc[4][4];  // [jt][it]
    #pragma unroll
    for (int a = 0; a < 4; ++a)
        #pragma unroll
        for (int b = 0; b < 4; ++b)
            acc[a][b] = (f32x4){0.f, 0.f, 0.f, 0.f};

    for (int k0 = 0; k0 < D_DIM; k0 += 64) {
        #pragma unroll
        for (int q = 0; q < 4; ++q) {
            GLOAD_LDS(fnh + (size_t)(i0 + q * 32 + srow) * D_DIM + k0 + sseg,
                      &As[q * 2048 + w * 512]);
            GLOAD_LDS(fnh + (size_t)(j0 + q * 32 + srow) * D_DIM + k0 + sseg,
                      &Bs[q * 2048 + w * 512]);
        }
        __syncthreads();

        #pragma unroll
        for (int kk = 0; kk < 2; ++kk) {
            const int swz = ((kk * 4 + grp) ^ (l15 & 7)) * 8;
            half8 aj[4], bi[4];
            #pragma unroll
            for (int jt = 0; jt < 4; ++jt)
                aj[jt] = *(const half8*)&Bs[(wc * 64 + jt * 16 + l15) * 64 + swz];
            #pragma unroll
            for (int it = 0; it < 4; ++it)
                bi[it] = *(const half8*)&As[(wr * 64 + it * 16 + l15) * 64 + swz];
            #pragma unroll
            for (int jt = 0; jt < 4; ++jt)
                #pragma unroll
                for (int it = 0; it < 4; ++it)
                    acc[jt][it] = __builtin_amdgcn_mfma_f32_16x16x32_f16(
                        aj[jt], bi[it], acc[jt][it], 0, 0, 0);
        }
        __syncthreads();
    }

    // Epilogue: lane owns row i = i0+wr*64+it*16+l15, j's = jb..jb+3 (float4).
    #pragma unroll
    for (int it = 0; it < 4; ++it) {
        const int i = i0 + wr * 64 + it * 16 + l15;
        const float* pmr = pm + (size_t)i * N_ROWS;
        const float* nmr = nm + (size_t)i * N_ROWS;
        float negp = 0.f, posp = 0.f, np = 0.f;
        #pragma unroll
        for (int jt = 0; jt < 4; ++jt) {
            const int jb = j0 + wc * 64 + jt * 16 + grp * 4;
            float4 pmv = *(const float4*)(pmr + jb);
            float4 nmv = *(const float4*)(nmr + jb);
            float pme[4] = {pmv.x, pmv.y, pmv.z, pmv.w};
            float nme[4] = {nmv.x, nmv.y, nmv.z, nmv.w};
            #pragma unroll
            for (int reg = 0; reg < 4; ++reg) {
                const int j = jb + reg;
                float cs   = acc[jt][it][reg] * INV_T;
                float keep = (i == j) ? 0.f : 1.f;
                float p    = pme[reg] * keep;
                float nv   = nme[reg] * keep;
                negp = fmaf(__expf(cs), nv, negp);
                posp = fmaf(cs, p, posp);
                np  += p;
            }
        }
        // reduce across the 4 grp lanes (lane bits 4,5)
        negp += __shfl_xor(negp, 16, 64);
        posp += __shfl_xor(posp, 16, 64);
        np   += __shfl_xor(np,   16, 64);
        negp += __shfl_xor(negp, 32, 64);
        posp += __shfl_xor(posp, 32, 64);
        np   += __shfl_xor(np,   32, 64);
        if (lane < 16) {
            atomicAdd(&accum[i], negp);
            atomicAdd(&accum[N_ROWS + i], posp);
            atomicAdd(&accum[2 * N_ROWS + i], np);
        }
    }
}

// ---------------------------------------------------------------------------
// K3: final reduction over rows -> scalar loss
// ---------------------------------------------------------------------------
__global__ __launch_bounds__(256) void final_k(const float* __restrict__ accum,
                                               float* __restrict__ out) {
    const int t = threadIdx.x;
    float s = 0.f;
    for (int i = t; i < N_ROWS; i += 256) {
        float neg  = accum[i];
        float posc = accum[N_ROWS + i];
        float np   = accum[2 * N_ROWS + i];
        float term = (np > 0.f) ? (posc - np * logf(fmaxf(neg, 1e-30f))) / np : 0.f;
        s += term;
    }
    #pragma unroll
    for (int off = 32; off > 0; off >>= 1) s += __shfl_xor(s, off, 64);
    __shared__ float wsum[4];
    if ((t & 63) == 0) wsum[t >> 6] = s;
    __syncthreads();
    if (t == 0) {
        float tot = wsum[0] + wsum[1] + wsum[2] + wsum[3];
        out[0] = -tot / (float)N_ROWS;
    }
}

// ---------------------------------------------------------------------------
extern "C" void kernel_launch(void* const* d_in, const int* in_sizes, int n_in,
                              void* d_out, int out_size, void* d_ws, size_t ws_size,
                              hipStream_t stream) {
    const float* feat = (const float*)d_in[0];
    const float* pm   = (const float*)d_in[1];
    const float* nm   = (const float*)d_in[2];
    float* out = (float*)d_out;

    _Float16* fnh = (_Float16*)d_ws;                         // N*D halfs (2 MB)
    float* accum  = (float*)(fnh + (size_t)N_ROWS * D_DIM);  // 3*N floats

    normalize_k<<<N_ROWS / 4, 256, 0, stream>>>(feat, fnh, accum);

    dim3 grid(N_ROWS / 128, N_ROWS / 128);
    fused_k<<<grid, 256, 0, stream>>>(fnh, pm, nm, accum);

    final_k<<<1, 256, 0, stream>>>(accum, out);
}

// Round 4
// 176.828 us; speedup vs baseline: 1.4820x; 1.0124x over previous
//
#include <hip/hip_runtime.h>
#include <math.h>

#define N_ROWS 4096
#define D_DIM  256
#define INV_T  (1.0f / 0.07f)

typedef _Float16 half8 __attribute__((ext_vector_type(8)));
typedef _Float16 half4 __attribute__((ext_vector_type(4)));
typedef float    f32x4 __attribute__((ext_vector_type(4)));

#define GLOAD_LDS(gp, lp) \
    __builtin_amdgcn_global_load_lds( \
        (const __attribute__((address_space(1))) void*)(gp), \
        (__attribute__((address_space(3))) void*)(lp), 16, 0, 0)

// ---------------------------------------------------------------------------
// K1: row-normalize features -> fp16 (one wave per row) + zero accum.
// ---------------------------------------------------------------------------
__global__ __launch_bounds__(256) void normalize_k(const float* __restrict__ f,
                                                   _Float16* __restrict__ fnh,
                                                   float* __restrict__ accum) {
    const int t   = threadIdx.x;
    const int gid = blockIdx.x * 256 + t;
    if (gid < 3 * N_ROWS) accum[gid] = 0.0f;

    const int lane = t & 63;
    const int row  = blockIdx.x * 4 + (t >> 6);
    float4 v = ((const float4*)(f + (size_t)row * D_DIM))[lane];
    float s = v.x * v.x + v.y * v.y + v.z * v.z + v.w * v.w;
    #pragma unroll
    for (int off = 32; off > 0; off >>= 1) s += __shfl_xor(s, off, 64);
    float rn = 1.0f / fmaxf(sqrtf(s), 1e-8f);
    half4 h;
    h.x = (_Float16)(v.x * rn);
    h.y = (_Float16)(v.y * rn);
    h.z = (_Float16)(v.z * rn);
    h.w = (_Float16)(v.w * rn);
    *(half4*)(fnh + (size_t)row * D_DIM + lane * 4) = h;
}

// ---------------------------------------------------------------------------
// K2: fused MFMA cosim + LDS cs round-trip + coalesced mask streaming.
// Phase 1 (K-loop): tile 128x128, BK=64, 4 waves, XOR-swizzled LDS staging
//   via global_load_lds (round-3 structure, 0 bank conflicts).
// Phase 2: dump cs = acc*INV_T as fp16 into the SAME 32 KB LDS (As/Bs dead),
//   16B-granule XOR swizzle (g ^ row&15) -> conflict-free.
// Phase 3: stream masks with thread->(row, 4 cols) mapping: each instruction
//   covers 2 rows x 512 B contiguous (vs round-3's 16 scattered 64 B rows).
// ---------------------------------------------------------------------------
__global__ __launch_bounds__(256, 4) void fused_k(const _Float16* __restrict__ fnh,
                                                  const float* __restrict__ pm,
                                                  const float* __restrict__ nm,
                                                  float* __restrict__ accum) {
    __shared__ __align__(16) _Float16 lds[128 * 128];  // 32 KB
    _Float16* As = lds;             // [128][64] during K-loop
    _Float16* Bs = lds + 128 * 64;  // [128][64] during K-loop

    const int t    = threadIdx.x;
    const int lane = t & 63;
    const int w    = t >> 6;
    const int wr   = w >> 1;
    const int wc   = w & 1;
    const int i0   = blockIdx.y * 128;
    const int j0   = blockIdx.x * 128;
    const int l15  = lane & 15;
    const int grp  = lane >> 4;

    // staging: 8 lanes/row, XOR-swizzled column segment (halfs)
    const int srow = t >> 3;
    const int sseg = ((t & 7) ^ ((t >> 3) & 7)) * 8;

    f32x4 acc[4][4];  // [jt][it]
    #pragma unroll
    for (int a = 0; a < 4; ++a)
        #pragma unroll
        for (int b = 0; b < 4; ++b)
            acc[a][b] = (f32x4){0.f, 0.f, 0.f, 0.f};

    for (int k0 = 0; k0 < D_DIM; k0 += 64) {
        #pragma unroll
        for (int q = 0; q < 4; ++q) {
            GLOAD_LDS(fnh + (size_t)(i0 + q * 32 + srow) * D_DIM + k0 + sseg,
                      &As[q * 2048 + w * 512]);
            GLOAD_LDS(fnh + (size_t)(j0 + q * 32 + srow) * D_DIM + k0 + sseg,
                      &Bs[q * 2048 + w * 512]);
        }
        __syncthreads();

        #pragma unroll
        for (int kk = 0; kk < 2; ++kk) {
            const int swz = ((kk * 4 + grp) ^ (l15 & 7)) * 8;
            half8 aj[4], bi[4];
            #pragma unroll
            for (int jt = 0; jt < 4; ++jt)
                aj[jt] = *(const half8*)&Bs[(wc * 64 + jt * 16 + l15) * 64 + swz];
            #pragma unroll
            for (int it = 0; it < 4; ++it)
                bi[it] = *(const half8*)&As[(wr * 64 + it * 16 + l15) * 64 + swz];
            #pragma unroll
            for (int jt = 0; jt < 4; ++jt)
                #pragma unroll
                for (int it = 0; it < 4; ++it)
                    acc[jt][it] = __builtin_amdgcn_mfma_f32_16x16x32_f16(
                        aj[jt], bi[it], acc[jt][it], 0, 0, 0);
        }
        __syncthreads();
    }

    // Phase 2: cs -> LDS as fp16. Element (i_loc, j_loc):
    //   i_loc = wr*64+it*16+l15, j_loc = wc*64+jt*16+grp*4+reg.
    // Row = 256 B = 16 granules of 16 B; granule g stored at slot g^(i_loc&15).
    #pragma unroll
    for (int it = 0; it < 4; ++it) {
        const int row = wr * 64 + it * 16 + l15;
        #pragma unroll
        for (int jt = 0; jt < 4; ++jt) {
            half4 h;
            h.x = (_Float16)(acc[jt][it][0] * INV_T);
            h.y = (_Float16)(acc[jt][it][1] * INV_T);
            h.z = (_Float16)(acc[jt][it][2] * INV_T);
            h.w = (_Float16)(acc[jt][it][3] * INV_T);
            const int g   = wc * 8 + jt * 2 + (grp >> 1);
            const int off = ((g ^ l15) << 4) | ((grp & 1) << 3);
            *(half4*)((char*)lds + row * 256 + off) = h;
        }
    }
    __syncthreads();

    // Phase 3: coalesced mask streaming. Thread t, step s:
    //   row r = s*8 + (t>>5), cols = (t&31)*4 .. +3.
    // Per instruction: 2 rows x 512 B contiguous mask bytes.
    const int lrow8 = t >> 5;
    const int lcol  = t & 31;
    const int gsw   = lcol >> 1;
    const int soff  = (lcol & 1) << 3;
    #pragma unroll
    for (int s = 0; s < 16; ++s) {
        const int r  = s * 8 + lrow8;
        const int i  = i0 + r;
        const int jb = j0 + lcol * 4;
        float4 pmv = *(const float4*)(pm + (size_t)i * N_ROWS + jb);
        float4 nmv = *(const float4*)(nm + (size_t)i * N_ROWS + jb);
        half4 h = *(const half4*)((const char*)lds + r * 256 +
                                  (((gsw ^ (r & 15)) << 4) | soff));
        float cse[4] = {(float)h.x, (float)h.y, (float)h.z, (float)h.w};
        float pme[4] = {pmv.x, pmv.y, pmv.z, pmv.w};
        float nme[4] = {nmv.x, nmv.y, nmv.z, nmv.w};
        float negp = 0.f, posp = 0.f, np = 0.f;
        #pragma unroll
        for (int e = 0; e < 4; ++e) {
            float keep = (i == jb + e) ? 0.f : 1.f;
            float p  = pme[e] * keep;
            float nv = nme[e] * keep;
            negp = fmaf(__expf(cse[e]), nv, negp);
            posp = fmaf(cse[e], p, posp);
            np  += p;
        }
        // reduce across the 32 lanes sharing this row (xor 1..16 stays in half)
        #pragma unroll
        for (int off = 1; off < 32; off <<= 1) {
            negp += __shfl_xor(negp, off, 64);
            posp += __shfl_xor(posp, off, 64);
            np   += __shfl_xor(np,   off, 64);
        }
        if (lcol == 0) {
            atomicAdd(&accum[i], negp);
            atomicAdd(&accum[N_ROWS + i], posp);
            atomicAdd(&accum[2 * N_ROWS + i], np);
        }
    }
}

// ---------------------------------------------------------------------------
// K3: final reduction over rows -> scalar loss
// ---------------------------------------------------------------------------
__global__ __launch_bounds__(256) void final_k(const float* __restrict__ accum,
                                               float* __restrict__ out) {
    const int t = threadIdx.x;
    float s = 0.f;
    for (int i = t; i < N_ROWS; i += 256) {
        float neg  = accum[i];
        float posc = accum[N_ROWS + i];
        float np   = accum[2 * N_ROWS + i];
        float term = (np > 0.f) ? (posc - np * logf(fmaxf(neg, 1e-30f))) / np : 0.f;
        s += term;
    }
    #pragma unroll
    for (int off = 32; off > 0; off >>= 1) s += __shfl_xor(s, off, 64);
    __shared__ float wsum[4];
    if ((t & 63) == 0) wsum[t >> 6] = s;
    __syncthreads();
    if (t == 0) {
        float tot = wsum[0] + wsum[1] + wsum[2] + wsum[3];
        out[0] = -tot / (float)N_ROWS;
    }
}

// ---------------------------------------------------------------------------
extern "C" void kernel_launch(void* const* d_in, const int* in_sizes, int n_in,
                              void* d_out, int out_size, void* d_ws, size_t ws_size,
                              hipStream_t stream) {
    const float* feat = (const float*)d_in[0];
    const float* pm   = (const float*)d_in[1];
    const float* nm   = (const float*)d_in[2];
    float* out = (float*)d_out;

    _Float16* fnh = (_Float16*)d_ws;                         // N*D halfs (2 MB)
    float* accum  = (float*)(fnh + (size_t)N_ROWS * D_DIM);  // 3*N floats

    normalize_k<<<N_ROWS / 4, 256, 0, stream>>>(feat, fnh, accum);

    dim3 grid(N_ROWS / 128, N_ROWS / 128);
    fused_k<<<grid, 256, 0, stream>>>(fnh, pm, nm, accum);

    final_k<<<1, 256, 0, stream>>>(accum, out);
}